// Round 13
// baseline (44.565 us; speedup 1.0000x reference)
//
#include <hip/hip_runtime.h>

#define S 1024
#define B 32
#define D 1024
#define NCH 64          // s-chunks (one per block)
#define CH (S / NCH)    // 16 rows per block
#define RPW 4           // rows per wave -- one tile, NO inner loop
#define ECH 8           // e-chunks
#define EC 128          // e per chunk

// ws layout (floats)
#define PG_OFF   0                          // pg: ECH*B*D (1 MB)
#define LOG_OFF  (PG_OFF + ECH * B * D)     // logits: B*S
#define MARR_OFF (LOG_OFF + B * S)          // NCH*B
#define LARR_OFF (MARR_OFF + NCH * B)       // NCH*B
#define PACC_OFF (LARR_OFF + NCH * B)       // NCH*B*D (8 MB)

// kG2: pg[ec][b][d] = sum_{e in chunk ec} h[b,e] * W[e,d].
// 256 blocks, W read exactly once, no atomics.
__global__ __launch_bounds__(256) void kG2(const float* __restrict__ hid,
                                           const float* __restrict__ W,
                                           float* __restrict__ ws) {
    const int tid = threadIdx.x;
    const int dc  = blockIdx.x;              // 32-d slice
    const int ec  = blockIdx.y;              // 128-e chunk
    __shared__ float h_sh[EC * 33];          // [e][b], padded
    #pragma unroll
    for (int k = 0; k < (EC * B) / 256; ++k) {
        int lin = tid + k * 256;
        int e = lin & (EC - 1);              // coalesced: e fastest in tid
        int b = lin >> 7;
        h_sh[e * 33 + b] = hid[b * D + ec * EC + e];
    }
    __syncthreads();

    const int b  = tid >> 3;                 // 0..31
    const int dq = tid & 7;                  // float4 within 32-d slice
    const float4* W4 = (const float4*)W;
    float4 a4 = {0.f, 0.f, 0.f, 0.f};
    #pragma unroll 8
    for (int e = 0; e < EC; ++e) {
        float  h = h_sh[e * 33 + b];
        float4 w = W4[(size_t)(ec * EC + e) * (D / 4) + dc * 8 + dq];
        a4.x = fmaf(h, w.x, a4.x);
        a4.y = fmaf(h, w.y, a4.y);
        a4.z = fmaf(h, w.z, a4.z);
        a4.w = fmaf(h, w.w, a4.w);
    }
    ((float4*)(ws + PG_OFF + ((size_t)ec * B + b) * D + dc * 32))[dq] = a4;
}

// kB: one softmax tile per wave, ALL enc loads issued upfront (no issue
// gating). 2048 blocks; wave = 4 rows; no online-softmax chain.
__global__ __launch_bounds__(256) void kB(const float* __restrict__ enc,
                                          float* __restrict__ ws) {
    const int tid  = threadIdx.x;
    const int lane = tid & 63;
    const int wid  = tid >> 6;
    const int c    = blockIdx.x;             // 0..NCH-1
    const int b    = blockIdx.y;

    float* pg     = ws + PG_OFF;
    float* logits = ws + LOG_OFF;
    float* marr   = ws + MARR_OFF;
    float* larr   = ws + LARR_OFF;
    float* pacc   = ws + PACC_OFF;

    __shared__ float4 g_sh[256];             // 4 KB
    __shared__ float4 sacc[4 * 256];         // 16 KB, merge
    __shared__ float sm[4], sl[4];

    // ---- issue ALL 16 enc loads (4 rows x 4 float4) upfront ----
    const float4* encb = (const float4*)enc;
    const int row0 = c * CH + wid * RPW;
    const size_t rstride = (size_t)B * (D / 4);
    size_t base = ((size_t)row0 * B + b) * (D / 4) + lane;

    float4 ev[16];
    #pragma unroll
    for (int r = 0; r < 4; ++r)
        #pragma unroll
        for (int j = 0; j < 4; ++j)
            ev[r * 4 + j] = encb[base + (size_t)r * rstride + j * 64];

    // ---- pg-reduce -> g_sh (hides enc latency); single barrier ----
    {
        float4 s4 = {0.f, 0.f, 0.f, 0.f};
        #pragma unroll
        for (int ec = 0; ec < ECH; ++ec) {
            float4 v = ((const float4*)(pg + (size_t)(ec * B + b) * D))[tid];
            s4.x += v.x; s4.y += v.y; s4.z += v.z; s4.w += v.w;
        }
        g_sh[tid] = s4;
    }
    __syncthreads();
    float4 gv[4];
    #pragma unroll
    for (int j = 0; j < 4; ++j) gv[j] = g_sh[j * 64 + lane];

    // ---- 4 dots, 4-way interleaved butterfly ----
    float d0 = 0.f, d1 = 0.f, d2 = 0.f, d3 = 0.f;
    #pragma unroll
    for (int j = 0; j < 4; ++j) {
        d0 += ev[0+j].x*gv[j].x + ev[0+j].y*gv[j].y + ev[0+j].z*gv[j].z + ev[0+j].w*gv[j].w;
        d1 += ev[4+j].x*gv[j].x + ev[4+j].y*gv[j].y + ev[4+j].z*gv[j].z + ev[4+j].w*gv[j].w;
        d2 += ev[8+j].x*gv[j].x + ev[8+j].y*gv[j].y + ev[8+j].z*gv[j].z + ev[8+j].w*gv[j].w;
        d3 += ev[12+j].x*gv[j].x + ev[12+j].y*gv[j].y + ev[12+j].z*gv[j].z + ev[12+j].w*gv[j].w;
    }
    #pragma unroll
    for (int off = 1; off < 64; off <<= 1) {
        d0 += __shfl_xor(d0, off, 64);
        d1 += __shfl_xor(d1, off, 64);
        d2 += __shfl_xor(d2, off, 64);
        d3 += __shfl_xor(d3, off, 64);
    }
    if (lane == 0) {
        logits[b * S + row0 + 0] = d0;
        logits[b * S + row0 + 1] = d1;
        logits[b * S + row0 + 2] = d2;
        logits[b * S + row0 + 3] = d3;
    }

    // ---- direct softmax tile (no running state) ----
    float m = fmaxf(fmaxf(d0, d1), fmaxf(d2, d3));
    float p0 = __expf(d0 - m), p1 = __expf(d1 - m),
          p2 = __expf(d2 - m), p3 = __expf(d3 - m);
    float l = (p0 + p1) + (p2 + p3);
    float4 acc[4];
    #pragma unroll
    for (int j = 0; j < 4; ++j) {
        acc[j].x = p0*ev[0+j].x + p1*ev[4+j].x + p2*ev[8+j].x + p3*ev[12+j].x;
        acc[j].y = p0*ev[0+j].y + p1*ev[4+j].y + p2*ev[8+j].y + p3*ev[12+j].y;
        acc[j].z = p0*ev[0+j].z + p1*ev[4+j].z + p2*ev[8+j].z + p3*ev[12+j].z;
        acc[j].w = p0*ev[0+j].w + p1*ev[4+j].w + p2*ev[8+j].w + p3*ev[12+j].w;
    }

    // ---- merge 4 waves -> block partial (m, l, acc) ----
    #pragma unroll
    for (int j = 0; j < 4; ++j) sacc[wid * 256 + j * 64 + lane] = acc[j];
    if (lane == 0) { sm[wid] = m; sl[wid] = l; }
    __syncthreads();
    float mg = fmaxf(fmaxf(sm[0], sm[1]), fmaxf(sm[2], sm[3]));
    float4 r = {0.f, 0.f, 0.f, 0.f};
    float lsum = 0.f;
    #pragma unroll
    for (int w = 0; w < 4; ++w) {
        float fw = __expf(sm[w] - mg);
        float4 a = sacc[w * 256 + wid * 64 + lane];
        r.x += a.x * fw; r.y += a.y * fw; r.z += a.z * fw; r.w += a.w * fw;
        lsum += sl[w] * fw;
    }
    ((float4*)pacc)[(size_t)(c * B + b) * (D / 4) + tid] = r;
    if (tid == 0) { marr[c * B + b] = mg; larr[c * B + b] = lsum; }
}

// kC: combine NCH partials -> reps; normalize logits -> alpha. Grid (4, B).
__global__ __launch_bounds__(256) void kC(float* __restrict__ out,
                                          const float* __restrict__ ws) {
    const int tid = threadIdx.x;
    const int q   = blockIdx.x;
    const int b   = blockIdx.y;
    const float* logits = ws + LOG_OFF;
    const float* marr   = ws + MARR_OFF;
    const float* larr   = ws + LARR_OFF;
    const float* pacc   = ws + PACC_OFF;

    __shared__ float shm[NCH], shl[NCH], shf[NCH];
    if (tid < NCH) { shm[tid] = marr[tid * B + b]; shl[tid] = larr[tid * B + b]; }
    __syncthreads();
    float mg = -3.0e38f;
    #pragma unroll
    for (int cc = 0; cc < NCH; ++cc) mg = fmaxf(mg, shm[cc]);
    if (tid < NCH) shf[tid] = __expf(shm[tid] - mg);
    __syncthreads();
    float lg = 0.f;
    #pragma unroll
    for (int cc = 0; cc < NCH; ++cc) lg += shl[cc] * shf[cc];
    const float inv = 1.f / lg;

    if (tid < 64) {            // reps quarter
        const int d4 = q * 64 + tid;
        float4 racc = {0.f, 0.f, 0.f, 0.f};
        #pragma unroll 4
        for (int cc = 0; cc < NCH; ++cc) {
            float  fc = shf[cc];
            float4 v  = ((const float4*)pacc)[(size_t)(cc * B + b) * (D / 4) + d4];
            racc.x += v.x * fc; racc.y += v.y * fc;
            racc.z += v.z * fc; racc.w += v.w * fc;
        }
        float4 rep = {racc.x * inv, racc.y * inv, racc.z * inv, racc.w * inv};
        ((float4*)out)[b * (D / 4) + d4] = rep;                    // reps [B,1,D]
    }
    const int s = q * 256 + tid;
    out[B * D + b * S + s] = __expf(logits[b * S + s] - mg) * inv; // alpha [B,1,S]
}

extern "C" void kernel_launch(void* const* d_in, const int* in_sizes, int n_in,
                              void* d_out, int out_size, void* d_ws, size_t ws_size,
                              hipStream_t stream) {
    const float* hid = (const float*)d_in[0];  // (2,B,H) flat == h[B, D]
    const float* enc = (const float*)d_in[1];  // (S,B,D)
    const float* W   = (const float*)d_in[2];  // (D,D)
    // d_in[3] = bias: per-b constant in logits -> cancels in softmax.

    float* out = (float*)d_out;
    float* ws  = (float*)d_ws;

    kG2<<<dim3(32, ECH), 256, 0, stream>>>(hid, W, ws);
    kB<<<dim3(NCH, B), 256, 0, stream>>>(enc, ws);
    kC<<<dim3(4, B), 256, 0, stream>>>(out, ws);
}

// Round 14
// 43.851 us; speedup vs baseline: 1.0163x; 1.0163x over previous
//
#include <hip/hip_runtime.h>
#include <stdint.h>

#define S 1024
#define B 32
#define D 1024
#define NCH 32           // s-chunks
#define CH (S / NCH)     // 32 rows per block
#define NPAIR (CH / 2)   // 16 pair-iterations
#define ECH 8            // e-chunks in kG
#define EC 128           // e per chunk

// ws layout (floats)
#define PG_OFF   0                          // pg: ECH*B*D (1 MB)
#define LOG_OFF  (PG_OFF + ECH * B * D)     // logits: B*S
#define MARR_OFF (LOG_OFF + B * S)          // NCH*B
#define LARR_OFF (MARR_OFF + NCH * B)       // NCH*B
#define PACC_OFF (LARR_OFF + NCH * B)       // NCH*B*D (4 MB)

typedef const __attribute__((address_space(1))) unsigned int* gas_t;
typedef __attribute__((address_space(3))) unsigned int* las_t;

// kG: pg[z][b][d] = sum_{e in chunk z} h[b,e] * W[e,d].  (R11's tied-best
// g-producer: 1024 blocks, W re-read 32x from L2/L3, full TLP.)
__global__ __launch_bounds__(256) void kG(const float* __restrict__ hid,
                                          const float* __restrict__ W,
                                          float* __restrict__ ws) {
    const int d  = blockIdx.x * 256 + threadIdx.x;
    const int b  = blockIdx.y;
    const int e0 = blockIdx.z * EC;
    const float* __restrict__ hrow = hid + b * D;
    float acc = 0.f;
    #pragma unroll 8
    for (int e = e0; e < e0 + EC; ++e)
        acc = fmaf(hrow[e], W[(size_t)e * D + d], acc);
    ws[PG_OFF + ((size_t)blockIdx.z * B + b) * D + d] = acc;
}

// kB: LDS-staged flash stream. Block (c,b): 16 pair-iterations over 32 rows.
// global_load_lds double-buffer (8 KB tiles); thread owns d-slice [4t,4t+4):
// gv, acc thread-private; softmax scalars computed redundantly; ONE barrier
// per iteration; no merge epilogue.
__global__ __launch_bounds__(256) void kB(const float* __restrict__ enc,
                                          float* __restrict__ ws) {
    const int tid  = threadIdx.x;
    const int lane = tid & 63;
    const int wid  = tid >> 6;
    const int c    = blockIdx.x;
    const int b    = blockIdx.y;

    float* pg     = ws + PG_OFF;
    float* logits = ws + LOG_OFF;
    float* marr   = ws + MARR_OFF;
    float* larr   = ws + LARR_OFF;
    float* pacc   = ws + PACC_OFF;

    __shared__ float tile[2][2 * D];        // 16 KB: dbuf x (2 rows x 1024)
    __shared__ float red[2][2][4];          // [iter&1][row][wave]

    const int row0 = c * CH;

    // stage a pair-tile: wave wid covers bytes [wid*1024, +1024) of each row
    auto stage = [&](int buf, int p) {
        #pragma unroll
        for (int r = 0; r < 2; ++r) {
            const float* gp = enc + ((size_t)(row0 + 2 * p + r) * B + b) * D
                            + wid * 256 + lane * 4;       // per-lane src
            float* lp = &tile[buf][r * D + wid * 256];    // wave-uniform dst
            __builtin_amdgcn_global_load_lds((gas_t)(uintptr_t)gp,
                                             (las_t)(uintptr_t)lp, 16, 0, 0);
        }
    };

    stage(0, 0);                             // tile[0] <- pair 0 (async)

    // gv = thread's float4 of g[b] = sum over 8 pg slices (L2-hot)
    float4 gv = {0.f, 0.f, 0.f, 0.f};
    #pragma unroll
    for (int ec = 0; ec < ECH; ++ec) {
        float4 v = ((const float4*)(pg + (size_t)(ec * B + b) * D))[tid];
        gv.x += v.x; gv.y += v.y; gv.z += v.z; gv.w += v.w;
    }
    __syncthreads();                         // tile[0] ready (vmcnt drained)

    float m = -3.0e38f, l = 0.f;
    float4 acc = {0.f, 0.f, 0.f, 0.f};

    for (int p = 0; p < NPAIR; ++p) {
        const int cur = p & 1;
        if (p + 1 < NPAIR) stage(cur ^ 1, p + 1);   // async prefetch

        const float4* t4 = (const float4*)tile[cur];
        float4 e0 = t4[tid];                 // row 0, this thread's d-slice
        float4 e1 = t4[256 + tid];           // row 1
        float pd0 = e0.x * gv.x + e0.y * gv.y + e0.z * gv.z + e0.w * gv.w;
        float pd1 = e1.x * gv.x + e1.y * gv.y + e1.z * gv.z + e1.w * gv.w;
        #pragma unroll
        for (int off = 1; off < 64; off <<= 1) {
            pd0 += __shfl_xor(pd0, off, 64);
            pd1 += __shfl_xor(pd1, off, 64);
        }
        if (lane == 0) { red[p & 1][0][wid] = pd0; red[p & 1][1][wid] = pd1; }
        __syncthreads();                     // red visible + next tile staged

        float l0 = red[p & 1][0][0] + red[p & 1][0][1]
                 + red[p & 1][0][2] + red[p & 1][0][3];
        float l1 = red[p & 1][1][0] + red[p & 1][1][1]
                 + red[p & 1][1][2] + red[p & 1][1][3];
        if (tid == 0) {
            logits[b * S + row0 + 2 * p]     = l0;
            logits[b * S + row0 + 2 * p + 1] = l1;
        }
        // online softmax over the pair (redundant scalars, identical/thread)
        float mn  = fmaxf(m, l0);
        float sc0 = __expf(m - mn);
        float pA  = __expf(l0 - mn);
        float mn2 = fmaxf(mn, l1);
        float sc1 = __expf(mn - mn2);
        float pB  = __expf(l1 - mn2);
        float s01 = sc0 * sc1;
        float a0  = pA * sc1;
        l = l * s01 + a0 + pB;
        acc.x = acc.x * s01 + a0 * e0.x + pB * e1.x;
        acc.y = acc.y * s01 + a0 * e0.y + pB * e1.y;
        acc.z = acc.z * s01 + a0 * e0.z + pB * e1.z;
        acc.w = acc.w * s01 + a0 * e0.w + pB * e1.w;
        m = mn2;
    }

    ((float4*)pacc)[(size_t)(c * B + b) * (D / 4) + tid] = acc;
    if (tid == 0) { marr[c * B + b] = m; larr[c * B + b] = l; }
}

// kC: combine NCH partials -> reps; normalize logits -> alpha. Grid (4, B).
__global__ __launch_bounds__(256) void kC(float* __restrict__ out,
                                          const float* __restrict__ ws) {
    const int tid = threadIdx.x;
    const int q   = blockIdx.x;
    const int b   = blockIdx.y;
    const float* logits = ws + LOG_OFF;
    const float* marr   = ws + MARR_OFF;
    const float* larr   = ws + LARR_OFF;
    const float* pacc   = ws + PACC_OFF;

    __shared__ float shm[NCH], shl[NCH], shf[NCH];
    if (tid < NCH) { shm[tid] = marr[tid * B + b]; shl[tid] = larr[tid * B + b]; }
    __syncthreads();
    float mg = -3.0e38f;
    #pragma unroll
    for (int cc = 0; cc < NCH; ++cc) mg = fmaxf(mg, shm[cc]);
    if (tid < NCH) shf[tid] = __expf(shm[tid] - mg);
    __syncthreads();
    float lg = 0.f;
    #pragma unroll
    for (int cc = 0; cc < NCH; ++cc) lg += shl[cc] * shf[cc];
    const float inv = 1.f / lg;

    if (tid < 64) {            // reps quarter
        const int d4 = q * 64 + tid;
        float4 racc = {0.f, 0.f, 0.f, 0.f};
        #pragma unroll 4
        for (int cc = 0; cc < NCH; ++cc) {
            float  fc = shf[cc];
            float4 v  = ((const float4*)pacc)[(size_t)(cc * B + b) * (D / 4) + d4];
            racc.x += v.x * fc; racc.y += v.y * fc;
            racc.z += v.z * fc; racc.w += v.w * fc;
        }
        float4 rep = {racc.x * inv, racc.y * inv, racc.z * inv, racc.w * inv};
        ((float4*)out)[b * (D / 4) + d4] = rep;                    // reps [B,1,D]
    }
    const int s = q * 256 + tid;
    out[B * D + b * S + s] = __expf(logits[b * S + s] - mg) * inv; // alpha [B,1,S]
}

extern "C" void kernel_launch(void* const* d_in, const int* in_sizes, int n_in,
                              void* d_out, int out_size, void* d_ws, size_t ws_size,
                              hipStream_t stream) {
    const float* hid = (const float*)d_in[0];  // (2,B,H) flat == h[B, D]
    const float* enc = (const float*)d_in[1];  // (S,B,D)
    const float* W   = (const float*)d_in[2];  // (D,D)
    // d_in[3] = bias: per-b constant in logits -> cancels in softmax.

    float* out = (float*)d_out;
    float* ws  = (float*)d_ws;

    kG<<<dim3(D / 256, B, ECH), 256, 0, stream>>>(hid, W, ws);
    kB<<<dim3(NCH, B), 256, 0, stream>>>(enc, ws);
    kC<<<dim3(4, B), 256, 0, stream>>>(out, ws);
}